// Round 12
// baseline (107.274 us; speedup 1.0000x reference)
//
#include <hip/hip_runtime.h>
#include <math.h>

typedef __attribute__((ext_vector_type(8))) short short8;
typedef __attribute__((ext_vector_type(4))) float f32x4;

#define BB 8192      // batch
#define CC 1000      // classes
#define NN 9192      // B + C real columns
#define NPAD 9216    // padded
#define DD 128       // feature dim
#define RB 64        // rows per block
#define NSPLIT 4     // column splits (blockIdx.y) -> grid 512 = 2 blocks/CU exactly
#define CPW 576      // columns per wave = 9216/(NSPLIT*4)
#define NT 36        // 16-col chunks per wave (divisible by 3 for 3-buffer rotation)
#define K2F 14.426950408889634f   // (1/T) * log2(e)

// ---- workspace layout (float offsets) ----
#define WS_BSUM  0        // [2048] per-block lp sums (corr)
#define WS_CLS   2048     // [1024] int batch histogram
#define WS_OFF   3072     // [1024] int CSR offsets
#define WS_CNT   4094     // [1] int completion ticket
#define WS_LIST  4096     // [9216] int CSR column lists
#define WS_RCP0  13312    // [9216] 1/cnt
#define WS_RCPD  22528    // [9216] 1/(cnt-1) - 1/cnt
#define WS_SPART 32768    // [4*8192]
#define WS_F2    98304    // fragment-major bf16 [9216*128]

static __device__ __forceinline__ unsigned short f2bf(float x) {
    unsigned int b = __float_as_uint(x);
    unsigned int r = (b + 0x7FFFu + ((b >> 16) & 1u)) >> 16;   // RNE
    return (unsigned short)r;
}
static __device__ __forceinline__ float fexp2(float x) {
    float r; asm("v_exp_f32 %0, %1" : "=v"(r) : "v"(x)); return r;
}
static __device__ __forceinline__ float flog2(float x) {
    float r; asm("v_log_f32 %0, %1" : "=v"(r) : "v"(x)); return r;
}
// element (row j, dim k) of fragment-major F2
static __device__ __forceinline__ float f2elem(const unsigned short* __restrict__ F2,
                                               int j, int k) {
    int u = ((j >> 4) * 4 + (k >> 5)) * 64 + ((k >> 3) & 3) * 16 + (j & 15);
    return __uint_as_float((unsigned int)F2[u * 8 + (k & 7)] << 16);
}

// ---- fused prep: blocks 0..143 convert fp32 -> fragment-major bf16;
//      block 144: hist + rcp tables + CSR via LDS fill + value-rank placement ----
__global__ __launch_bounds__(1024) void prep_kernel(
    const float* __restrict__ feats, const float* __restrict__ ctrs,
    const int* __restrict__ tgt, unsigned short* __restrict__ F2,
    int* __restrict__ cls, int* __restrict__ off, int* __restrict__ list,
    float* __restrict__ rcp0, float* __restrict__ rcpd, int* __restrict__ cnt)
{
    const int tid = threadIdx.x;
    if (blockIdx.x < 144) {
        // cvt: one short8-unit per thread.  F2 fragment-major: 16B unit
        // u = (j16*4 + ks)*64 + l4*16 + l15 holds (col j=j16*16+l15, k=ks*32+l4*8..+8)
        int u = blockIdx.x * 1024 + tid;          // < 147456 = NPAD*16
        int j = u >> 4, quad = u & 15;
        int k0 = quad * 8;
        float4 v0 = {0.f,0.f,0.f,0.f}, v1 = {0.f,0.f,0.f,0.f};
        if (j < BB) {
            v0 = *(const float4*)&feats[(size_t)j * DD + k0];
            v1 = *(const float4*)&feats[(size_t)j * DD + k0 + 4];
        } else if (j < NN) {
            v0 = *(const float4*)&ctrs[(size_t)(j - BB) * DD + k0];
            v1 = *(const float4*)&ctrs[(size_t)(j - BB) * DD + k0 + 4];
        }
        short8 o;
        o[0]=f2bf(v0.x); o[1]=f2bf(v0.y); o[2]=f2bf(v0.z); o[3]=f2bf(v0.w);
        o[4]=f2bf(v1.x); o[5]=f2bf(v1.y); o[6]=f2bf(v1.z); o[7]=f2bf(v1.w);
        size_t offb = (size_t)((((j >> 4) * 4 + (quad >> 2)) * 64 + (quad & 3) * 16 + (j & 15)) * 8);
        *(short8*)&F2[offb] = o;
        return;
    }

    // ---- setup block (runs concurrently with the cvt blocks) ----
    __shared__ int h[1024];
    __shared__ int s[1024];
    __shared__ int cur[1024];
    __shared__ int llds[NPAD];    // CSR list staged in LDS (36 KB)

    if (tid == 0) *cnt = 0;       // reset corr completion ticket (poison-safe)
    h[tid] = 0;
    __syncthreads();
    for (int i = tid; i < BB; i += 1024) atomicAdd(&h[tgt[i]], 1);
    __syncthreads();

    const int cnt_b = h[tid];            // batch members of class tid
    cls[tid] = cnt_b;

    // per-column weights
    for (int j = tid; j < NPAD; j += 1024) {
        if (j < NN) {
            int c = (j < BB) ? tgt[j] : (j - BB);
            int n = h[c] + 1;            // +1: the class center itself
            float a = 1.0f / (float)n;
            rcp0[j] = a;
            rcpd[j] = ((n > 1) ? 1.0f / (float)(n - 1) : 0.0f) - a;
        } else { rcp0[j] = 0.0f; rcpd[j] = 0.0f; }
    }

    // exclusive scan of segment lengths (members + center)
    int v = (tid < CC) ? cnt_b + 1 : 0;
    s[tid] = v;
    __syncthreads();
    for (int d = 1; d < 1024; d <<= 1) {
        int t = (tid >= d) ? s[tid - d] : 0;
        __syncthreads();
        s[tid] += t;
        __syncthreads();
    }
    const int o = s[tid] - v;
    if (tid < CC) { off[tid] = o; cur[tid] = o; }
    __syncthreads();

    // fill CSR segments in LDS (order within segment nondeterministic)
    for (int j = tid; j < NN; j += 1024) {
        int c = (j < BB) ? tgt[j] : (j - BB);
        int r = atomicAdd(&cur[c], 1);
        llds[r] = j;
    }
    __syncthreads();

    // value-rank placement: deterministic sorted order, parallel over elements
    for (int p = tid; p < NN; p += 1024) {
        int e = llds[p];
        int c = (e < BB) ? tgt[e] : (e - BB);
        int ob = (c > 0) ? s[c - 1] : 0;          // segment base (inclusive-scan shift)
        int n = h[c] + 1;
        int rank = 0;
        for (int m = 0; m < n; ++m) rank += (llds[ob + m] < e);
        list[ob + rank] = e;
    }
}

// one 16-col x 32-k fragment group (4 x 1KB coalesced loads)
static __device__ __forceinline__ void loadB(const unsigned short* __restrict__ F2,
                                             int j0, int lane8, short8 (&buf)[4]) {
#pragma unroll
    for (int ks = 0; ks < 4; ++ks)
        buf[ks] = *(const short8*)&F2[(size_t)(((j0 >> 4) * 4 + ks) * 512 + lane8)];
}

// 16 MFMAs: 64 rows x 16 cols x full K=128
static __device__ __forceinline__ void mfma16(const short8 (&af)[4][4], const short8 (&b)[4],
                                              f32x4 (&acc)[4]) {
    const f32x4 z4 = {0.f, 0.f, 0.f, 0.f};
#pragma unroll
    for (int fm = 0; fm < 4; ++fm)
        acc[fm] = __builtin_amdgcn_mfma_f32_16x16x32_bf16(af[0][fm], b[0], z4, 0, 0, 0);
#pragma unroll
    for (int ks = 1; ks < 4; ++ks)
#pragma unroll
        for (int fm = 0; fm < 4; ++fm)
            acc[fm] = __builtin_amdgcn_mfma_f32_16x16x32_bf16(
                af[ks][fm], b[ks], acc[fm], 0, 0, 0);
}

// 3 VALU per element: fma -> v_exp -> fmac  (no masks, no metadata)
static __device__ __forceinline__ void epi16(const f32x4 (&acc)[4], float r0, float (&Sl)[16]) {
#pragma unroll
    for (int fm = 0; fm < 4; ++fm)
#pragma unroll
        for (int q = 0; q < 4; ++q) {
            float l2 = fmaf(acc[fm][q], K2F, -K2F);
            Sl[fm * 4 + q] = fmaf(fexp2(l2), r0, Sl[fm * 4 + q]);
        }
}

__global__ __launch_bounds__(256, 2) void main_kernel(
    const unsigned short* __restrict__ F2, const float* __restrict__ rcp0,
    float* __restrict__ S_part)
{
    __shared__ float combS[3][64];

    const int tid  = threadIdx.x;
    const int lane = tid & 63;
    const int wave = tid >> 6;
    const int l15 = lane & 15, l4 = lane >> 4;
    const int lane8 = lane * 8;
    const int row0 = blockIdx.x * RB;
    const int split = blockIdx.y;
    const int cb = (split * 4 + wave) * CPW;     // this wave's column base

    // A fragments straight from global (rows row0..row0+63), persistent
    short8 af[4][4];                             // [ks][fm]
#pragma unroll
    for (int fm = 0; fm < 4; ++fm)
#pragma unroll
        for (int ks = 0; ks < 4; ++ks)
            af[ks][fm] = *(const short8*)&F2[(size_t)((((row0 >> 4) + fm) * 4 + ks) * 512 + lane8)];

    float Sl[16];
#pragma unroll
    for (int x = 0; x < 16; ++x) Sl[x] = 0.f;

    // 3-buffer rotation, 2-deep prefetch (all names compile-time indexed)
    short8 b0[4], b1[4], b2[4];
    float r00, r01, r02;
    loadB(F2, cb, lane8, b0);       r00 = rcp0[cb + l15];
    loadB(F2, cb + 16, lane8, b1);  r01 = rcp0[cb + 16 + l15];

#pragma unroll 1
    for (int tt = 0; tt < NT; tt += 3) {
        {
            if (tt + 2 < NT) { int j = cb + (tt + 2) * 16; loadB(F2, j, lane8, b2); r02 = rcp0[j + l15]; }
            f32x4 acc[4];
            mfma16(af, b0, acc);
            epi16(acc, r00, Sl);
        }
        {
            if (tt + 3 < NT) { int j = cb + (tt + 3) * 16; loadB(F2, j, lane8, b0); r00 = rcp0[j + l15]; }
            f32x4 acc[4];
            mfma16(af, b1, acc);
            epi16(acc, r01, Sl);
        }
        {
            if (tt + 4 < NT) { int j = cb + (tt + 4) * 16; loadB(F2, j, lane8, b1); r01 = rcp0[j + l15]; }
            f32x4 acc[4];
            mfma16(af, b2, acc);
            epi16(acc, r02, Sl);
        }
    }

    // 16-lane column reduce (tree), then cross-wave combine via tiny LDS
#pragma unroll
    for (int idx = 0; idx < 16; ++idx) {
        float S = Sl[idx];
#pragma unroll
        for (int off = 1; off < 16; off <<= 1) S += __shfl_xor(S, off, 64);
        Sl[idx] = S;
        if (wave > 0 && l15 == 0) {
            int rl = (idx >> 2) * 16 + l4 * 4 + (idx & 3);
            combS[wave - 1][rl] = S;
        }
    }
    __syncthreads();
    if (wave == 0 && l15 == 0) {
#pragma unroll
        for (int idx = 0; idx < 16; ++idx) {
            int rl = (idx >> 2) * 16 + l4 * 4 + (idx & 3);
            S_part[split * BB + row0 + rl] = Sl[idx] + combS[0][rl] + combS[1][rl] + combS[2][rl];
        }
    }
}

// one wave per row: sparse mask correction + P + final lp; last block reduces all
__global__ __launch_bounds__(256) void corr_kernel(
    const unsigned short* __restrict__ F2, const int* __restrict__ tgt,
    const int* __restrict__ cls, const int* __restrict__ off,
    const int* __restrict__ list, const float* __restrict__ rcp0,
    const float* __restrict__ rcpd, const float* __restrict__ S_part,
    float* __restrict__ bsum, int* __restrict__ cnt, float* __restrict__ out)
{
    __shared__ float wred[4];
    __shared__ int lastflag;
    const int wave = threadIdx.x >> 6, lane = threadIdx.x & 63;
    const int i = blockIdx.x * 4 + wave;
    const int c = tgt[i];
    const int n = cls[c];                         // = npos (>=1: row i itself)
    const int o = off[c];
    const int k0 = lane * 2;
    const float fa = f2elem(F2, i, k0), fb = f2elem(F2, i, k0 + 1);

    float CorrS = 0.f, P = 0.f;
    for (int idx = 0; idx <= n; ++idx) {          // n batch members + 1 center
        int j = list[o + idx];
        float d = fa * f2elem(F2, j, k0) + fb * f2elem(F2, j, k0 + 1);
#pragma unroll
        for (int s = 1; s < 64; s <<= 1) d += __shfl_xor(d, s, 64);
        float e = fexp2(fmaf(d, K2F, -K2F));
        if (j == i) CorrS -= e * rcp0[i];         // remove self from S0
        else        { CorrS += e * rcpd[j]; P += d; }
    }
    float S = CorrS;
#pragma unroll
    for (int s = 0; s < NSPLIT; ++s) S += S_part[s * BB + i];
    float lp = fmaf(K2F, P / (float)n, -K2F) - flog2(S);   // log2 units

    if (lane == 0) wred[wave] = lp;
    __syncthreads();
    if (threadIdx.x == 0) {
        bsum[blockIdx.x] = wred[0] + wred[1] + wred[2] + wred[3];
        __threadfence();                          // release bsum before ticket
        lastflag = (atomicAdd(cnt, 1) == gridDim.x - 1) ? 1 : 0;
    }
    __syncthreads();
    if (lastflag) {                               // exactly one block runs this
        __threadfence();                          // acquire all bsum writes
        const int tid = threadIdx.x;
        float v = 0.f;
#pragma unroll
        for (int q = 0; q < 8; ++q) v += bsum[tid * 8 + q];   // fixed order
#pragma unroll
        for (int offt = 1; offt < 64; offt <<= 1) v += __shfl_xor(v, offt, 64);
        __shared__ float wsum[4];
        if (lane == 0) wsum[wave] = v;
        __syncthreads();
        if (tid == 0) {
            float t = wsum[0] + wsum[1] + wsum[2] + wsum[3];
            out[0] = -0.6931471805599453f * (t / (float)BB);  // ln2 * mean, negated
            *cnt = 0;                             // reset for next replay
        }
    }
}

extern "C" void kernel_launch(void* const* d_in, const int* in_sizes, int n_in,
                              void* d_out, int out_size, void* d_ws, size_t ws_size,
                              hipStream_t stream) {
    const float* ctrs  = (const float*)d_in[0];   // centers1 [1000,128]
    const float* feats = (const float*)d_in[1];   // features [8192,128]
    const int*   tgt   = (const int*)d_in[2];     // targets  [8192] int32
    float* out = (float*)d_out;
    float* ws  = (float*)d_ws;

    float* bsum = ws + WS_BSUM;
    int*   cls  = (int*)(ws + WS_CLS);
    int*   off  = (int*)(ws + WS_OFF);
    int*   cnt  = (int*)(ws + WS_CNT);
    int*   list = (int*)(ws + WS_LIST);
    float* rcp0 = ws + WS_RCP0;
    float* rcpd = ws + WS_RCPD;
    float* Sp   = ws + WS_SPART;
    unsigned short* F2 = (unsigned short*)(ws + WS_F2);

    prep_kernel<<<dim3(145), dim3(1024), 0, stream>>>(feats, ctrs, tgt, F2, cls, off, list, rcp0, rcpd, cnt);
    main_kernel<<<dim3(BB / RB, NSPLIT), dim3(256), 0, stream>>>(F2, rcp0, Sp);
    corr_kernel<<<dim3(BB / 4), dim3(256), 0, stream>>>(F2, tgt, cls, off, list, rcp0, rcpd, Sp, bsum, cnt, out);
}

// Round 13
// 47.597 us; speedup vs baseline: 2.2538x; 2.2538x over previous
//
#include <hip/hip_runtime.h>
#include <math.h>

typedef __attribute__((ext_vector_type(8))) short short8;
typedef __attribute__((ext_vector_type(4))) float f32x4;

#define BB 8192      // batch
#define CC 1000      // classes
#define NN 9192      // B + C real columns
#define NPAD 9216    // padded
#define DD 128       // feature dim
#define RB 64        // rows per block
#define NSPLIT 4     // column splits (blockIdx.y) -> grid 512 = 2 blocks/CU exactly
#define CPW 576      // columns per wave = 9216/(NSPLIT*4)
#define NT 36        // 16-col chunks per wave (divisible by 3 for 3-buffer rotation)
#define K2F 14.426950408889634f   // (1/T) * log2(e)

// ---- workspace layout (float offsets) ----
#define WS_CLS   0        // [1024] int batch histogram
#define WS_TCOL  1024     // [9216] int per-column class
#define WS_RCP0  10240    // [9216] 1/cnt
#define WS_RCP1  19456    // [9216] 1/(cnt-1)
#define WS_SPART 28672    // [4*8192]
#define WS_PPART 61440    // [4*8192]
#define WS_F2    94208    // fragment-major bf16 [9216*128]

static __device__ __forceinline__ unsigned short f2bf(float x) {
    unsigned int b = __float_as_uint(x);
    unsigned int r = (b + 0x7FFFu + ((b >> 16) & 1u)) >> 16;   // RNE
    return (unsigned short)r;
}
static __device__ __forceinline__ float fexp2(float x) {
    float r; asm("v_exp_f32 %0, %1" : "=v"(r) : "v"(x)); return r;
}
static __device__ __forceinline__ float flog2(float x) {
    float r; asm("v_log_f32 %0, %1" : "=v"(r) : "v"(x)); return r;
}

// ---- fused prep: blocks 0..143 convert fp32 -> fragment-major bf16;
//      block 144: histogram + per-column class/weight tables (no CSR needed) ----
__global__ __launch_bounds__(1024) void prep_kernel(
    const float* __restrict__ feats, const float* __restrict__ ctrs,
    const int* __restrict__ tgt, unsigned short* __restrict__ F2,
    int* __restrict__ cls, int* __restrict__ tcol,
    float* __restrict__ rcp0, float* __restrict__ rcp1)
{
    const int tid = threadIdx.x;
    if (blockIdx.x < 144) {
        // cvt: one short8-unit per thread.  F2 fragment-major: 16B unit
        // u = (j16*4 + ks)*64 + l4*16 + l15 holds (col j=j16*16+l15, k=ks*32+l4*8..+8)
        int u = blockIdx.x * 1024 + tid;          // < 147456 = NPAD*16
        int j = u >> 4, quad = u & 15;
        int k0 = quad * 8;
        float4 v0 = {0.f,0.f,0.f,0.f}, v1 = {0.f,0.f,0.f,0.f};
        if (j < BB) {
            v0 = *(const float4*)&feats[(size_t)j * DD + k0];
            v1 = *(const float4*)&feats[(size_t)j * DD + k0 + 4];
        } else if (j < NN) {
            v0 = *(const float4*)&ctrs[(size_t)(j - BB) * DD + k0];
            v1 = *(const float4*)&ctrs[(size_t)(j - BB) * DD + k0 + 4];
        }
        short8 o;
        o[0]=f2bf(v0.x); o[1]=f2bf(v0.y); o[2]=f2bf(v0.z); o[3]=f2bf(v0.w);
        o[4]=f2bf(v1.x); o[5]=f2bf(v1.y); o[6]=f2bf(v1.z); o[7]=f2bf(v1.w);
        size_t offb = (size_t)((((j >> 4) * 4 + (quad >> 2)) * 64 + (quad & 3) * 16 + (j & 15)) * 8);
        *(short8*)&F2[offb] = o;
        return;
    }

    // ---- setup block (runs concurrently with the cvt blocks) ----
    __shared__ int h[1024];
    h[tid] = 0;
    __syncthreads();
    for (int i = tid; i < BB; i += 1024) atomicAdd(&h[tgt[i]], 1);
    __syncthreads();

    cls[tid] = h[tid];                    // npos for rows of class tid

    for (int j = tid; j < NPAD; j += 1024) {
        if (j < NN) {
            int c = (j < BB) ? tgt[j] : (j - BB);
            int n = h[c] + 1;             // +1: the class center itself
            tcol[j] = c;
            rcp0[j] = 1.0f / (float)n;
            rcp1[j] = (n > 1) ? 1.0f / (float)(n - 1) : 0.0f;
        } else { tcol[j] = -2; rcp0[j] = 0.0f; rcp1[j] = 0.0f; }
    }
}

// one 16-col x 32-k fragment group (4 x 1KB coalesced loads)
static __device__ __forceinline__ void loadB(const unsigned short* __restrict__ F2,
                                             int j0, int lane8, short8 (&buf)[4]) {
#pragma unroll
    for (int ks = 0; ks < 4; ++ks)
        buf[ks] = *(const short8*)&F2[(size_t)(((j0 >> 4) * 4 + ks) * 512 + lane8)];
}

// 16 MFMAs: 64 rows x 16 cols x full K=128
static __device__ __forceinline__ void mfma16(const short8 (&af)[4][4], const short8 (&b)[4],
                                              f32x4 (&acc)[4]) {
    const f32x4 z4 = {0.f, 0.f, 0.f, 0.f};
#pragma unroll
    for (int fm = 0; fm < 4; ++fm)
        acc[fm] = __builtin_amdgcn_mfma_f32_16x16x32_bf16(af[0][fm], b[0], z4, 0, 0, 0);
#pragma unroll
    for (int ks = 1; ks < 4; ++ks)
#pragma unroll
        for (int fm = 0; fm < 4; ++fm)
            acc[fm] = __builtin_amdgcn_mfma_f32_16x16x32_bf16(
                af[ks][fm], b[ks], acc[fm], 0, 0, 0);
}

// fused mask epilogue: ~7 VALU per element (cmp/cndmask handle the mask inline)
template<bool DIAG>
static __device__ __forceinline__ void epi16(const f32x4 (&acc)[4], float r0, float r1,
                                             int tj, int j0, int l15, int rowbase,
                                             const int (&ti)[16],
                                             float (&Sl)[16], float (&Pl)[16]) {
    const int col = j0 + l15;
#pragma unroll
    for (int fm = 0; fm < 4; ++fm)
#pragma unroll
        for (int q = 0; q < 4; ++q) {
            const int x = fm * 4 + q;
            float d = acc[fm][q];
            float l2 = fmaf(d, K2F, -K2F);
            float e = fexp2(l2);
            bool m = (tj == ti[x]);
            if (DIAG) {
                bool self = (col == rowbase + fm * 16 + q);
                if (self) { e = 0.f; m = false; }
            }
            float rw = m ? r1 : r0;
            Sl[x] = fmaf(e, rw, Sl[x]);       // padded cols: rcp=0
            Pl[x] += m ? d : 0.f;             // sum of masked raw dots
        }
}

__global__ __launch_bounds__(256, 2) void main_kernel(
    const unsigned short* __restrict__ F2, const int* __restrict__ tcol,
    const float* __restrict__ rcp0, const float* __restrict__ rcp1,
    float* __restrict__ S_part, float* __restrict__ P_part)
{
    __shared__ float combS[3][64], combP[3][64];

    const int tid  = threadIdx.x;
    const int lane = tid & 63;
    const int wave = tid >> 6;
    const int l15 = lane & 15, l4 = lane >> 4;
    const int lane8 = lane * 8;
    const int row0 = blockIdx.x * RB;
    const int split = blockIdx.y;
    const int cb = (split * 4 + wave) * CPW;     // this wave's column base
    const int rowbase = row0 + l4 * 4;

    // A fragments straight from global (rows row0..row0+63), persistent
    short8 af[4][4];                             // [ks][fm]
#pragma unroll
    for (int fm = 0; fm < 4; ++fm)
#pragma unroll
        for (int ks = 0; ks < 4; ++ks)
            af[ks][fm] = *(const short8*)&F2[(size_t)((((row0 >> 4) + fm) * 4 + ks) * 512 + lane8)];

    int ti[16];                                  // row classes for this lane's 16 rows
#pragma unroll
    for (int fm = 0; fm < 4; ++fm)
#pragma unroll
        for (int q = 0; q < 4; ++q)
            ti[fm * 4 + q] = tcol[rowbase + fm * 16 + q];

    float Sl[16], Pl[16];
#pragma unroll
    for (int x = 0; x < 16; ++x) { Sl[x] = 0.f; Pl[x] = 0.f; }

    // 3-buffer rotation, 2-deep prefetch (all names compile-time indexed)
    short8 b0[4], b1[4], b2[4];
    float r0A, r0B, r0C, r1A, r1B, r1C;
    int tjA, tjB, tjC;
    loadB(F2, cb, lane8, b0);
    r0A = rcp0[cb + l15]; r1A = rcp1[cb + l15]; tjA = tcol[cb + l15];
    loadB(F2, cb + 16, lane8, b1);
    r0B = rcp0[cb + 16 + l15]; r1B = rcp1[cb + 16 + l15]; tjB = tcol[cb + 16 + l15];

#pragma unroll 1
    for (int tt = 0; tt < NT; tt += 3) {
        {
            if (tt + 2 < NT) {
                int j = cb + (tt + 2) * 16;
                loadB(F2, j, lane8, b2);
                r0C = rcp0[j + l15]; r1C = rcp1[j + l15]; tjC = tcol[j + l15];
            }
            const int j0 = cb + tt * 16;
            f32x4 acc[4];
            mfma16(af, b0, acc);
            if ((unsigned)(j0 - row0) < 64u)
                epi16<true >(acc, r0A, r1A, tjA, j0, l15, rowbase, ti, Sl, Pl);
            else
                epi16<false>(acc, r0A, r1A, tjA, j0, l15, rowbase, ti, Sl, Pl);
        }
        {
            if (tt + 3 < NT) {
                int j = cb + (tt + 3) * 16;
                loadB(F2, j, lane8, b0);
                r0A = rcp0[j + l15]; r1A = rcp1[j + l15]; tjA = tcol[j + l15];
            }
            const int j0 = cb + (tt + 1) * 16;
            f32x4 acc[4];
            mfma16(af, b1, acc);
            if ((unsigned)(j0 - row0) < 64u)
                epi16<true >(acc, r0B, r1B, tjB, j0, l15, rowbase, ti, Sl, Pl);
            else
                epi16<false>(acc, r0B, r1B, tjB, j0, l15, rowbase, ti, Sl, Pl);
        }
        {
            if (tt + 4 < NT) {
                int j = cb + (tt + 4) * 16;
                loadB(F2, j, lane8, b1);
                r0B = rcp0[j + l15]; r1B = rcp1[j + l15]; tjB = tcol[j + l15];
            }
            const int j0 = cb + (tt + 2) * 16;
            f32x4 acc[4];
            mfma16(af, b2, acc);
            if ((unsigned)(j0 - row0) < 64u)
                epi16<true >(acc, r0C, r1C, tjC, j0, l15, rowbase, ti, Sl, Pl);
            else
                epi16<false>(acc, r0C, r1C, tjC, j0, l15, rowbase, ti, Sl, Pl);
        }
    }

    // 16-lane column reduce (tree), then cross-wave combine via tiny LDS
#pragma unroll
    for (int idx = 0; idx < 16; ++idx) {
        float S = Sl[idx], P = Pl[idx];
#pragma unroll
        for (int off = 1; off < 16; off <<= 1) {
            S += __shfl_xor(S, off, 64);
            P += __shfl_xor(P, off, 64);
        }
        Sl[idx] = S; Pl[idx] = P;
        if (wave > 0 && l15 == 0) {
            int rl = (idx >> 2) * 16 + l4 * 4 + (idx & 3);
            combS[wave - 1][rl] = S;
            combP[wave - 1][rl] = P;
        }
    }
    __syncthreads();
    if (wave == 0 && l15 == 0) {
#pragma unroll
        for (int idx = 0; idx < 16; ++idx) {
            int rl = (idx >> 2) * 16 + l4 * 4 + (idx & 3);
            S_part[split * BB + row0 + rl] = Sl[idx] + combS[0][rl] + combS[1][rl] + combS[2][rl];
            P_part[split * BB + row0 + rl] = Pl[idx] + combP[0][rl] + combP[1][rl] + combP[2][rl];
        }
    }
}

// one block: combine split partials, per-row lp, mean, write scalar
__global__ __launch_bounds__(1024) void final_kernel(
    const int* __restrict__ tgt, const int* __restrict__ cls,
    const float* __restrict__ S_part, const float* __restrict__ P_part,
    float* __restrict__ out)
{
    const int tid = threadIdx.x;
    float lpsum = 0.f;
    for (int i = tid; i < BB; i += 1024) {
        float S = 0.f, P = 0.f;
#pragma unroll
        for (int s = 0; s < NSPLIT; ++s) {
            S += S_part[s * BB + i];
            P += P_part[s * BB + i];
        }
        const float npos = (float)cls[tgt[i]];
        lpsum += fmaf(K2F, P / npos, -K2F) - flog2(S);   // log2 units
    }
#pragma unroll
    for (int off = 1; off < 64; off <<= 1) lpsum += __shfl_xor(lpsum, off, 64);
    __shared__ float wsum[16];
    if ((tid & 63) == 0) wsum[tid >> 6] = lpsum;
    __syncthreads();
    if (tid == 0) {
        float t = 0.f;
#pragma unroll
        for (int w = 0; w < 16; ++w) t += wsum[w];
        out[0] = -0.6931471805599453f * (t / (float)BB);   // ln2 * mean, negated
    }
}

extern "C" void kernel_launch(void* const* d_in, const int* in_sizes, int n_in,
                              void* d_out, int out_size, void* d_ws, size_t ws_size,
                              hipStream_t stream) {
    const float* ctrs  = (const float*)d_in[0];   // centers1 [1000,128]
    const float* feats = (const float*)d_in[1];   // features [8192,128]
    const int*   tgt   = (const int*)d_in[2];     // targets  [8192] int32
    float* out = (float*)d_out;
    float* ws  = (float*)d_ws;

    int*   cls  = (int*)(ws + WS_CLS);
    int*   tcol = (int*)(ws + WS_TCOL);
    float* rcp0 = ws + WS_RCP0;
    float* rcp1 = ws + WS_RCP1;
    float* Sp   = ws + WS_SPART;
    float* Pp   = ws + WS_PPART;
    unsigned short* F2 = (unsigned short*)(ws + WS_F2);

    prep_kernel<<<dim3(145), dim3(1024), 0, stream>>>(feats, ctrs, tgt, F2, cls, tcol, rcp0, rcp1);
    main_kernel<<<dim3(BB / RB, NSPLIT), dim3(256), 0, stream>>>(F2, tcol, rcp0, rcp1, Sp, Pp);
    final_kernel<<<dim3(1), dim3(1024), 0, stream>>>(tgt, cls, Sp, Pp, out);
}